// Round 1
// baseline (365.551 us; speedup 1.0000x reference)
//
#include <hip/hip_runtime.h>

#define T_SEQ 512
#define INPUT 14
#define HID 8
#define GATES 32
#define TC 16
#define NCHUNK (T_SEQ / TC)
#define BN_EPS 1e-5f

__device__ __forceinline__ float fast_exp2(float x) { return __builtin_amdgcn_exp2f(x); }
__device__ __forceinline__ float fast_rcp(float x)  { return __builtin_amdgcn_rcpf(x); }

// Block: 256 threads = 4 waves; each wave handles 2 batch elements (32 lanes each).
// Lane g in [0,32): unit = g&7, type = g>>3 (0=i,1=f,2=g,3=o) -- PyTorch gate order.
__global__ __launch_bounds__(256, 2)
void lstm_forex_kernel(const float* __restrict__ x,
                       const float* __restrict__ Wih1, const float* __restrict__ Whh1,
                       const float* __restrict__ bih1, const float* __restrict__ bhh1,
                       const float* __restrict__ Wih2, const float* __restrict__ Whh2,
                       const float* __restrict__ bih2, const float* __restrict__ bhh2,
                       const float* __restrict__ bn_gamma, const float* __restrict__ bn_beta,
                       const float* __restrict__ bn_mean, const float* __restrict__ bn_var,
                       const float* __restrict__ w1p, const float* __restrict__ b1p,
                       const float* __restrict__ w2p, const float* __restrict__ b2p,
                       float* __restrict__ out)
{
    __shared__ float xbuf[4][2][TC][16];   // [wave][elem][t][14 padded to 16]
    __shared__ float gbuf[4][2][GATES];    // activated gates, unit-major: idx = unit*4+type
    __shared__ float hbuf1[4][2][8];
    __shared__ float hbuf2[4][2][8];

    const int tid  = threadIdx.x;
    const int wave = tid >> 6;
    const int lane = tid & 63;
    const int grp  = lane >> 5;          // which of the wave's 2 batch elements
    const int g    = lane & 31;          // gate row index
    const int unit = g & 7;
    const int type = g >> 3;

    const int b = blockIdx.x * 8 + wave * 2 + grp;

    // ---- per-lane weight rows (registers) ----
    float wi1[INPUT], wh1[HID], wi2[HID], wh2[HID];
#pragma unroll
    for (int k = 0; k < INPUT; ++k) wi1[k] = Wih1[g * INPUT + k];
#pragma unroll
    for (int j = 0; j < HID; ++j) wh1[j] = Whh1[g * HID + j];
#pragma unroll
    for (int j = 0; j < HID; ++j) wi2[j] = Wih2[g * HID + j];
#pragma unroll
    for (int j = 0; j < HID; ++j) wh2[j] = Whh2[g * HID + j];
    const float bsum1 = bih1[g] + bhh1[g];
    const float bsum2 = bih2[g] + bhh2[g];

    // branch-free activation constants: sigmoid for i,f,o; tanh for g (type==2)
    const float actScale = (type == 2) ? -2.885390082f : -1.4426950408f;
    const float actMul   = (type == 2) ? 2.f : 1.f;
    const float actAdd   = (type == 2) ? -1.f : 0.f;

    // ---- x staging: 448 dwords per wave-chunk (2 elems * 16 t * 14), 7 per lane ----
    const float* gptr[7];
    int loff[7];
#pragma unroll
    for (int it = 0; it < 7; ++it) {
        int d   = it * 64 + lane;       // coalesced flat dword index within wave-chunk
        int es  = d / 224;              // which elem
        int idx = d - es * 224;         // dword within elem's 16x14 chunk
        int tr  = idx / 14;
        int k   = idx - tr * 14;
        int bb  = blockIdx.x * 8 + wave * 2 + es;
        gptr[it] = x + (size_t)bb * (T_SEQ * INPUT) + idx;
        loff[it] = es * (TC * 16) + tr * 16 + k;   // padded LDS layout
    }

    float h1[HID], h2v[HID];
    float c1 = 0.f, c2 = 0.f;
#pragma unroll
    for (int j = 0; j < HID; ++j) { h1[j] = 0.f; h2v[j] = 0.f; }

    // prefetch chunk 0
    float st[7];
#pragma unroll
    for (int it = 0; it < 7; ++it) { st[it] = *gptr[it]; gptr[it] += TC * INPUT; }

    float (*xw)[TC][16] = xbuf[wave];
    float* gw  = gbuf[wave][grp];
    float* h1w = hbuf1[wave][grp];
    float* h2w = hbuf2[wave][grp];

    for (int c = 0; c < NCHUNK; ++c) {
        // stage chunk c into LDS (in-order DS per wave makes this visible to reads below)
#pragma unroll
        for (int it = 0; it < 7; ++it) ((float*)xw)[loff[it]] = st[it];
        // prefetch chunk c+1 while computing chunk c
        if (c + 1 < NCHUNK) {
#pragma unroll
            for (int it = 0; it < 7; ++it) { st[it] = *gptr[it]; gptr[it] += TC * INPUT; }
        }
        __builtin_amdgcn_wave_barrier();

#pragma unroll
        for (int t = 0; t < TC; ++t) {
            const float* xrow = &xw[grp][t][0];
            float4 xa = *(const float4*)(xrow + 0);
            float4 xb = *(const float4*)(xrow + 4);
            float4 xc = *(const float4*)(xrow + 8);
            float2 xd = *(const float2*)(xrow + 12);

            // ---- layer 1 gate pre-activation ----
            float a0 = bsum1, a1 = 0.f;
            a0 = fmaf(xa.x, wi1[0], a0);  a1 = fmaf(xa.y, wi1[1], a1);
            a0 = fmaf(xa.z, wi1[2], a0);  a1 = fmaf(xa.w, wi1[3], a1);
            a0 = fmaf(xb.x, wi1[4], a0);  a1 = fmaf(xb.y, wi1[5], a1);
            a0 = fmaf(xb.z, wi1[6], a0);  a1 = fmaf(xb.w, wi1[7], a1);
            a0 = fmaf(xc.x, wi1[8], a0);  a1 = fmaf(xc.y, wi1[9], a1);
            a0 = fmaf(xc.z, wi1[10], a0); a1 = fmaf(xc.w, wi1[11], a1);
            a0 = fmaf(xd.x, wi1[12], a0); a1 = fmaf(xd.y, wi1[13], a1);
#pragma unroll
            for (int j = 0; j < HID; j += 2) {
                a0 = fmaf(h1[j],     wh1[j],     a0);
                a1 = fmaf(h1[j + 1], wh1[j + 1], a1);
            }
            float acc = a0 + a1;

            float av = fmaf(fast_rcp(1.f + fast_exp2(actScale * acc)), actMul, actAdd);
            gw[(unit << 2) + type] = av;
            __builtin_amdgcn_wave_barrier();
            float4 gv = *(const float4*)&gw[unit << 2];   // (i,f,g,o) activated
            c1 = fmaf(gv.y, c1, gv.x * gv.z);
            float th1 = fmaf(fast_rcp(1.f + fast_exp2(-2.885390082f * c1)), 2.f, -1.f);
            float hn1 = gv.w * th1;
            if (type == 0) h1w[unit] = hn1;
            __builtin_amdgcn_wave_barrier();
            float4 ha = *(const float4*)&h1w[0];
            float4 hb = *(const float4*)&h1w[4];
            h1[0] = ha.x; h1[1] = ha.y; h1[2] = ha.z; h1[3] = ha.w;
            h1[4] = hb.x; h1[5] = hb.y; h1[6] = hb.z; h1[7] = hb.w;

            // ---- layer 2 ----
            float p0 = bsum2, p1 = 0.f;
#pragma unroll
            for (int j = 0; j < HID; j += 2) {
                p0 = fmaf(h1[j],      wi2[j],     p0);
                p1 = fmaf(h1[j + 1],  wi2[j + 1], p1);
            }
#pragma unroll
            for (int j = 0; j < HID; j += 2) {
                p0 = fmaf(h2v[j],     wh2[j],     p0);
                p1 = fmaf(h2v[j + 1], wh2[j + 1], p1);
            }
            float acc2 = p0 + p1;

            float av2 = fmaf(fast_rcp(1.f + fast_exp2(actScale * acc2)), actMul, actAdd);
            __builtin_amdgcn_wave_barrier();
            gw[(unit << 2) + type] = av2;
            __builtin_amdgcn_wave_barrier();
            float4 gv2 = *(const float4*)&gw[unit << 2];
            c2 = fmaf(gv2.y, c2, gv2.x * gv2.z);
            float th2 = fmaf(fast_rcp(1.f + fast_exp2(-2.885390082f * c2)), 2.f, -1.f);
            float hn2 = gv2.w * th2;
            if (type == 0) h2w[unit] = hn2;
            __builtin_amdgcn_wave_barrier();
            float4 h2a = *(const float4*)&h2w[0];
            float4 h2b = *(const float4*)&h2w[4];
            h2v[0] = h2a.x; h2v[1] = h2a.y; h2v[2] = h2a.z; h2v[3] = h2a.w;
            h2v[4] = h2b.x; h2v[5] = h2b.y; h2v[6] = h2b.z; h2v[7] = h2b.w;
        }
    }

    // ---- BN (eval) + MLP head, one lane per batch element ----
    if (g == 0) {
        float nd[HID];
#pragma unroll
        for (int j = 0; j < HID; ++j) {
            float inv = 1.f / sqrtf(bn_var[j] + BN_EPS);
            nd[j] = bn_gamma[j] * (h2v[j] - bn_mean[j]) * inv + bn_beta[j];
        }
        float acc = b2p[0];
#pragma unroll
        for (int m = 0; m < 4; ++m) {
            float s = b1p[m];
#pragma unroll
            for (int j = 0; j < HID; ++j) s = fmaf(nd[j], w1p[m * HID + j], s);
            s = fmaxf(s, 0.f);
            acc = fmaf(s, w2p[m], acc);
        }
        out[b] = acc;
    }
}

extern "C" void kernel_launch(void* const* d_in, const int* in_sizes, int n_in,
                              void* d_out, int out_size, void* d_ws, size_t ws_size,
                              hipStream_t stream) {
    const float* x        = (const float*)d_in[0];
    const float* Wih1     = (const float*)d_in[1];
    const float* Whh1     = (const float*)d_in[2];
    const float* bih1     = (const float*)d_in[3];
    const float* bhh1     = (const float*)d_in[4];
    const float* Wih2     = (const float*)d_in[5];
    const float* Whh2     = (const float*)d_in[6];
    const float* bih2     = (const float*)d_in[7];
    const float* bhh2     = (const float*)d_in[8];
    const float* bn_gamma = (const float*)d_in[9];
    const float* bn_beta  = (const float*)d_in[10];
    const float* bn_mean  = (const float*)d_in[11];
    const float* bn_var   = (const float*)d_in[12];
    const float* w1p      = (const float*)d_in[13];
    const float* b1p      = (const float*)d_in[14];
    const float* w2p      = (const float*)d_in[15];
    const float* b2p      = (const float*)d_in[16];
    float* out = (float*)d_out;

    const int B = in_sizes[0] / (T_SEQ * INPUT);   // 4096
    dim3 grid(B / 8), block(256);
    hipLaunchKernelGGL(lstm_forex_kernel, grid, block, 0, stream,
                       x, Wih1, Whh1, bih1, bhh1, Wih2, Whh2, bih2, bhh2,
                       bn_gamma, bn_beta, bn_mean, bn_var, w1p, b1p, w2p, b2p, out);
}

// Round 3
// 352.952 us; speedup vs baseline: 1.0357x; 1.0357x over previous
//
#include <hip/hip_runtime.h>

#define T_SEQ 512
#define INPUT 14
#define HID 8
#define TC 16
#define NCHUNK (T_SEQ / TC)
#define BN_EPS 1e-5f

__device__ __forceinline__ float fast_exp2(float x) { return __builtin_amdgcn_exp2f(x); }
__device__ __forceinline__ float fast_rcp(float x)  { return __builtin_amdgcn_rcpf(x); }

// ds_swizzle with compile-time pattern (BitMode: offset = xor<<10 | or<<5 | and)
template <int IMM>
__device__ __forceinline__ float swz(float v) {
    return __int_as_float(__builtin_amdgcn_ds_swizzle(__float_as_int(v), IMM));
}

// Block: 256 threads = 4 waves; each wave handles 2 batch elements (32 lanes each).
// Lane g in [0,32): unit = g&7, type = g>>3 (0=i,1=f,2=g,3=o) -- PyTorch gate order.
// All cross-lane exchange via ds_swizzle (no LDS gate arrays, no barriers in hot loop).
__global__ __launch_bounds__(256, 2)
void lstm_forex_kernel(const float* __restrict__ x,
                       const float* __restrict__ Wih1, const float* __restrict__ Whh1,
                       const float* __restrict__ bih1, const float* __restrict__ bhh1,
                       const float* __restrict__ Wih2, const float* __restrict__ Whh2,
                       const float* __restrict__ bih2, const float* __restrict__ bhh2,
                       const float* __restrict__ bn_gamma, const float* __restrict__ bn_beta,
                       const float* __restrict__ bn_mean, const float* __restrict__ bn_var,
                       const float* __restrict__ w1p, const float* __restrict__ b1p,
                       const float* __restrict__ w2p, const float* __restrict__ b2p,
                       float* __restrict__ out)
{
    __shared__ float xbuf[4][2][TC][16];   // [wave][elem][t][14 padded to 16]

    const int tid  = threadIdx.x;
    const int wave = tid >> 6;
    const int lane = tid & 63;
    const int grp  = lane >> 5;          // which of the wave's 2 batch elements
    const int g    = lane & 31;          // gate row index
    const int type = g >> 3;
    const bool b0  = (type & 1) != 0;
    const bool b1  = (type & 2) != 0;

    const int b = blockIdx.x * 8 + wave * 2 + grp;

    // ---- per-lane weight rows (registers) ----
    float wi1[INPUT], wh1[HID], wi2[HID], wh2[HID];
#pragma unroll
    for (int k = 0; k < INPUT; ++k) wi1[k] = Wih1[g * INPUT + k];
#pragma unroll
    for (int j = 0; j < HID; ++j) wh1[j] = Whh1[g * HID + j];
#pragma unroll
    for (int j = 0; j < HID; ++j) wi2[j] = Wih2[g * HID + j];
#pragma unroll
    for (int j = 0; j < HID; ++j) wh2[j] = Whh2[g * HID + j];
    const float bsum1 = bih1[g] + bhh1[g];
    const float bsum2 = bih2[g] + bhh2[g];

    // branch-free activation constants: sigmoid for i,f,o; tanh for g (type==2)
    const float actScale = (type == 2) ? -2.885390082f : -1.4426950408f;
    const float actMul   = (type == 2) ? 2.f : 1.f;
    const float actAdd   = (type == 2) ? -1.f : 0.f;

    // ---- x staging: 448 dwords per wave-chunk (2 elems * 16 t * 14), 7 per lane ----
    const float* gptr[7];
    int loff[7];
#pragma unroll
    for (int it = 0; it < 7; ++it) {
        int d   = it * 64 + lane;       // coalesced flat dword index within wave-chunk
        int es  = d / 224;              // which elem
        int idx = d - es * 224;         // dword within elem's 16x14 chunk
        int tr  = idx / 14;
        int k   = idx - tr * 14;
        int bb  = blockIdx.x * 8 + wave * 2 + es;
        gptr[it] = x + (size_t)bb * (T_SEQ * INPUT) + idx;
        loff[it] = es * (TC * 16) + tr * 16 + k;   // padded LDS layout
    }

    float h1[HID], h2v[HID];
    float c1 = 0.f, c2 = 0.f;
#pragma unroll
    for (int j = 0; j < HID; ++j) { h1[j] = 0.f; h2v[j] = 0.f; }

    // prefetch chunk 0
    float st[7];
#pragma unroll
    for (int it = 0; it < 7; ++it) { st[it] = *gptr[it]; gptr[it] += TC * INPUT; }

    float (*xw)[TC][16] = xbuf[wave];

    for (int c = 0; c < NCHUNK; ++c) {
        // stage chunk c into LDS (in-order DS per wave makes this visible to reads below)
#pragma unroll
        for (int it = 0; it < 7; ++it) ((float*)xw)[loff[it]] = st[it];
        // prefetch chunk c+1 while computing chunk c
        if (c + 1 < NCHUNK) {
#pragma unroll
            for (int it = 0; it < 7; ++it) { st[it] = *gptr[it]; gptr[it] += TC * INPUT; }
        }
        __builtin_amdgcn_wave_barrier();

#pragma unroll
        for (int t = 0; t < TC; ++t) {
            const float* xrow = &xw[grp][t][0];
            float4 xa = *(const float4*)(xrow + 0);
            float4 xb = *(const float4*)(xrow + 4);
            float4 xc = *(const float4*)(xrow + 8);
            float2 xd = *(const float2*)(xrow + 12);

            // ---- layer 1 gate pre-activation (x part off critical path) ----
            float a0 = bsum1, a1 = 0.f;
            a0 = fmaf(xa.x, wi1[0], a0);  a1 = fmaf(xa.y, wi1[1], a1);
            a0 = fmaf(xa.z, wi1[2], a0);  a1 = fmaf(xa.w, wi1[3], a1);
            a0 = fmaf(xb.x, wi1[4], a0);  a1 = fmaf(xb.y, wi1[5], a1);
            a0 = fmaf(xb.z, wi1[6], a0);  a1 = fmaf(xb.w, wi1[7], a1);
            a0 = fmaf(xc.x, wi1[8], a0);  a1 = fmaf(xc.y, wi1[9], a1);
            a0 = fmaf(xc.z, wi1[10], a0); a1 = fmaf(xc.w, wi1[11], a1);
            a0 = fmaf(xd.x, wi1[12], a0); a1 = fmaf(xd.y, wi1[13], a1);
            // layer-2 recurrent part is also independent of this step's chain
            float q0 = bsum2, q1 = 0.f;
#pragma unroll
            for (int j = 0; j < HID; j += 2) {
                q0 = fmaf(h2v[j],     wh2[j],     q0);
                q1 = fmaf(h2v[j + 1], wh2[j + 1], q1);
            }
#pragma unroll
            for (int j = 0; j < HID; j += 2) {
                a0 = fmaf(h1[j],     wh1[j],     a0);
                a1 = fmaf(h1[j + 1], wh1[j + 1], a1);
            }
            float acc = a0 + a1;

            // own-type activation (sigmoid for i,f,o; tanh for g)
            float v0 = fmaf(fast_rcp(1.f + fast_exp2(actScale * acc)), actMul, actAdd);
            // gate exchange: xor-swizzles deliver activation of type^1, type^2, type^3
            float v1 = swz<0x201F>(v0);   // xor 8
            float v2 = swz<0x401F>(v0);   // xor 16
            float v3 = swz<0x601F>(v0);   // xor 24
            // P = sigmoid(i)*tanh(g), F = sigmoid(f), O = sigmoid(o)
            float P = b0 ? v1 * v3 : v0 * v2;
            float F = b1 ? (b0 ? v2 : v3) : (b0 ? v0 : v1);
            float O = b1 ? (b0 ? v0 : v1) : (b0 ? v2 : v3);
            c1 = fmaf(F, c1, P);
            float th1 = fmaf(fast_rcp(1.f + fast_exp2(-2.885390082f * c1)), 2.f, -1.f);
            float h1u = O * th1;   // every lane holds h1[unit]
            // h1 broadcast: src lane = (lane & 0x18) | j  -> imm = (j<<5)|0x18
            h1[0] = swz<0x18>(h1u); h1[1] = swz<0x38>(h1u);
            h1[2] = swz<0x58>(h1u); h1[3] = swz<0x78>(h1u);
            h1[4] = swz<0x98>(h1u); h1[5] = swz<0xB8>(h1u);
            h1[6] = swz<0xD8>(h1u); h1[7] = swz<0xF8>(h1u);

            // ---- layer 2 ----
            float p0 = q0, p1 = q1;
#pragma unroll
            for (int j = 0; j < HID; j += 2) {
                p0 = fmaf(h1[j],     wi2[j],     p0);
                p1 = fmaf(h1[j + 1], wi2[j + 1], p1);
            }
            float acc2 = p0 + p1;

            float u0 = fmaf(fast_rcp(1.f + fast_exp2(actScale * acc2)), actMul, actAdd);
            float u1 = swz<0x201F>(u0);
            float u2 = swz<0x401F>(u0);
            float u3 = swz<0x601F>(u0);
            float P2 = b0 ? u1 * u3 : u0 * u2;
            float F2 = b1 ? (b0 ? u2 : u3) : (b0 ? u0 : u1);
            float O2 = b1 ? (b0 ? u0 : u1) : (b0 ? u2 : u3);
            c2 = fmaf(F2, c2, P2);
            float th2 = fmaf(fast_rcp(1.f + fast_exp2(-2.885390082f * c2)), 2.f, -1.f);
            float h2u = O2 * th2;
            h2v[0] = swz<0x18>(h2u); h2v[1] = swz<0x38>(h2u);
            h2v[2] = swz<0x58>(h2u); h2v[3] = swz<0x78>(h2u);
            h2v[4] = swz<0x98>(h2u); h2v[5] = swz<0xB8>(h2u);
            h2v[6] = swz<0xD8>(h2u); h2v[7] = swz<0xF8>(h2u);
        }
    }

    // ---- BN (eval) + MLP head, one lane per batch element ----
    if (g == 0) {
        float nd[HID];
#pragma unroll
        for (int j = 0; j < HID; ++j) {
            float inv = 1.f / sqrtf(bn_var[j] + BN_EPS);
            nd[j] = bn_gamma[j] * (h2v[j] - bn_mean[j]) * inv + bn_beta[j];
        }
        float acc = b2p[0];
#pragma unroll
        for (int m = 0; m < 4; ++m) {
            float s = b1p[m];
#pragma unroll
            for (int j = 0; j < HID; ++j) s = fmaf(nd[j], w1p[m * HID + j], s);
            s = fmaxf(s, 0.f);
            acc = fmaf(s, w2p[m], acc);
        }
        out[b] = acc;
    }
}

extern "C" void kernel_launch(void* const* d_in, const int* in_sizes, int n_in,
                              void* d_out, int out_size, void* d_ws, size_t ws_size,
                              hipStream_t stream) {
    const float* x        = (const float*)d_in[0];
    const float* Wih1     = (const float*)d_in[1];
    const float* Whh1     = (const float*)d_in[2];
    const float* bih1     = (const float*)d_in[3];
    const float* bhh1     = (const float*)d_in[4];
    const float* Wih2     = (const float*)d_in[5];
    const float* Whh2     = (const float*)d_in[6];
    const float* bih2     = (const float*)d_in[7];
    const float* bhh2     = (const float*)d_in[8];
    const float* bn_gamma = (const float*)d_in[9];
    const float* bn_beta  = (const float*)d_in[10];
    const float* bn_mean  = (const float*)d_in[11];
    const float* bn_var   = (const float*)d_in[12];
    const float* w1p      = (const float*)d_in[13];
    const float* b1p      = (const float*)d_in[14];
    const float* w2p      = (const float*)d_in[15];
    const float* b2p      = (const float*)d_in[16];
    float* out = (float*)d_out;

    const int B = in_sizes[0] / (T_SEQ * INPUT);   // 4096
    dim3 grid(B / 8), block(256);
    hipLaunchKernelGGL(lstm_forex_kernel, grid, block, 0, stream,
                       x, Wih1, Whh1, bih1, bhh1, Wih2, Whh2, bih2, bhh2,
                       bn_gamma, bn_beta, bn_mean, bn_var, w1p, b1p, w2p, b2p, out);
}

// Round 4
// 352.214 us; speedup vs baseline: 1.0379x; 1.0021x over previous
//
#include <hip/hip_runtime.h>

#define T_SEQ 512
#define INPUT 14
#define HID 8
#define TC 16
#define NCHUNK (T_SEQ / TC)
#define BN_EPS 1e-5f

__device__ __forceinline__ float fast_exp2(float x) { return __builtin_amdgcn_exp2f(x); }
__device__ __forceinline__ float fast_rcp(float x)  { return __builtin_amdgcn_rcpf(x); }

// ds_swizzle (LDS pipe) -- only used for xor16, which DPP cannot express
template <int IMM>
__device__ __forceinline__ float swz(float v) {
    return __int_as_float(__builtin_amdgcn_ds_swizzle(__float_as_int(v), IMM));
}

// DPP cross-lane ops (VALU pipe, ~4 cyc latency vs ~60 for DS ops)
#define DPP_XOR1 0xB1   // quad_perm [1,0,3,2]
#define DPP_XOR2 0x4E   // quad_perm [2,3,0,1]
#define DPP_XOR3 0x1B   // quad_perm [3,2,1,0]
#define DPP_XOR7 0x141  // row_half_mirror: lane ^= 7 within 8-group
#define DPP_XOR8 0x128  // row_ror:8: lane ^= 8 within 16-row
template <int CTRL>
__device__ __forceinline__ float dpp(float v) {
    return __int_as_float(__builtin_amdgcn_update_dpp(
        0, __float_as_int(v), CTRL, 0xF, 0xF, true));
}

// Produce hx[m] = value of h at lane (g ^ m), m in [0,8): 7 DPP movs, depth 2.
__device__ __forceinline__ void butterfly8(float h, float (&hx)[8]) {
    hx[0] = h;
    hx[1] = dpp<DPP_XOR1>(h);
    hx[2] = dpp<DPP_XOR2>(h);
    hx[3] = dpp<DPP_XOR3>(h);
    float h7 = dpp<DPP_XOR7>(h);
    hx[7] = h7;
    hx[4] = dpp<DPP_XOR3>(h7);   // xor 3 of xor 7 = xor 4
    hx[5] = dpp<DPP_XOR2>(h7);   // xor 5
    hx[6] = dpp<DPP_XOR1>(h7);   // xor 6
}

// Block: 256 threads = 4 waves; each wave handles 2 batch elements (32 lanes each).
// Lane g in [0,32): unit = g&7, type = g>>3 (0=i,1=f,2=g,3=o) -- PyTorch gate order.
// Cross-lane exchange: DPP (VALU) for everything except xor16 (1 swizzle/layer).
// Recurrent dots use XOR-butterfly with per-lane pre-permuted weights:
//   sum_j h[j]*W[g][j] == sum_m (h at lane g^m) * W[g][u^m]
__global__ __launch_bounds__(256, 2)
void lstm_forex_kernel(const float* __restrict__ x,
                       const float* __restrict__ Wih1, const float* __restrict__ Whh1,
                       const float* __restrict__ bih1, const float* __restrict__ bhh1,
                       const float* __restrict__ Wih2, const float* __restrict__ Whh2,
                       const float* __restrict__ bih2, const float* __restrict__ bhh2,
                       const float* __restrict__ bn_gamma, const float* __restrict__ bn_beta,
                       const float* __restrict__ bn_mean, const float* __restrict__ bn_var,
                       const float* __restrict__ w1p, const float* __restrict__ b1p,
                       const float* __restrict__ w2p, const float* __restrict__ b2p,
                       float* __restrict__ out)
{
    __shared__ float xbuf[4][2][TC][16];   // [wave][elem][t][14 padded to 16]

    const int tid  = threadIdx.x;
    const int wave = tid >> 6;
    const int lane = tid & 63;
    const int grp  = lane >> 5;          // which of the wave's 2 batch elements
    const int g    = lane & 31;          // gate row index
    const int u    = g & 7;
    const int type = g >> 3;
    const bool b0  = (type & 1) != 0;
    const bool b1  = (type & 2) != 0;

    const int b = blockIdx.x * 8 + wave * 2 + grp;

    // ---- per-lane weight rows; recurrent mats pre-permuted for XOR butterfly ----
    float wi1[INPUT], wh1p[8], wi2p[8], wh2p[8];
#pragma unroll
    for (int k = 0; k < INPUT; ++k) wi1[k] = Wih1[g * INPUT + k];
#pragma unroll
    for (int m = 0; m < 8; ++m) {
        int j = u ^ m;
        wh1p[m] = Whh1[g * HID + j];
        wi2p[m] = Wih2[g * HID + j];
        wh2p[m] = Whh2[g * HID + j];
    }
    const float bsum1 = bih1[g] + bhh1[g];
    const float bsum2 = bih2[g] + bhh2[g];

    // branch-free activation constants: sigmoid for i,f,o; tanh for g (type==2)
    const float actScale = (type == 2) ? -2.885390082f : -1.4426950408f;
    const float actMul   = (type == 2) ? 2.f : 1.f;
    const float actAdd   = (type == 2) ? -1.f : 0.f;

    // ---- x staging: 448 dwords per wave-chunk (2 elems * 16 t * 14), 7 per lane ----
    const float* gptr[7];
    int loff[7];
#pragma unroll
    for (int it = 0; it < 7; ++it) {
        int d   = it * 64 + lane;       // coalesced flat dword index within wave-chunk
        int es  = d / 224;              // which elem
        int idx = d - es * 224;         // dword within elem's 16x14 chunk
        int tr  = idx / 14;
        int k   = idx - tr * 14;
        int bb  = blockIdx.x * 8 + wave * 2 + es;
        gptr[it] = x + (size_t)bb * (T_SEQ * INPUT) + idx;
        loff[it] = es * (TC * 16) + tr * 16 + k;   // padded LDS layout
    }

    float hx1[8], hx2[8];               // butterfly images of h1, h2
    float c1 = 0.f, c2 = 0.f;
#pragma unroll
    for (int m = 0; m < 8; ++m) { hx1[m] = 0.f; hx2[m] = 0.f; }

    // prefetch chunk 0
    float st[7];
#pragma unroll
    for (int it = 0; it < 7; ++it) { st[it] = *gptr[it]; gptr[it] += TC * INPUT; }

    float (*xw)[TC][16] = xbuf[wave];

    for (int c = 0; c < NCHUNK; ++c) {
        // stage chunk c into LDS (in-order DS per wave makes this visible to reads below)
#pragma unroll
        for (int it = 0; it < 7; ++it) ((float*)xw)[loff[it]] = st[it];
        // prefetch chunk c+1 while computing chunk c
        if (c + 1 < NCHUNK) {
#pragma unroll
            for (int it = 0; it < 7; ++it) { st[it] = *gptr[it]; gptr[it] += TC * INPUT; }
        }
        __builtin_amdgcn_wave_barrier();

#pragma unroll
        for (int t = 0; t < TC; ++t) {
            const float* xrow = &xw[grp][t][0];
            float4 xa = *(const float4*)(xrow + 0);
            float4 xb = *(const float4*)(xrow + 4);
            float4 xc = *(const float4*)(xrow + 8);
            float2 xd = *(const float2*)(xrow + 12);

            // ---- layer 1 gate pre-activation (x part off critical path) ----
            float a0 = bsum1, a1 = 0.f;
            a0 = fmaf(xa.x, wi1[0], a0);  a1 = fmaf(xa.y, wi1[1], a1);
            a0 = fmaf(xa.z, wi1[2], a0);  a1 = fmaf(xa.w, wi1[3], a1);
            a0 = fmaf(xb.x, wi1[4], a0);  a1 = fmaf(xb.y, wi1[5], a1);
            a0 = fmaf(xb.z, wi1[6], a0);  a1 = fmaf(xb.w, wi1[7], a1);
            a0 = fmaf(xc.x, wi1[8], a0);  a1 = fmaf(xc.y, wi1[9], a1);
            a0 = fmaf(xc.z, wi1[10], a0); a1 = fmaf(xc.w, wi1[11], a1);
            a0 = fmaf(xd.x, wi1[12], a0); a1 = fmaf(xd.y, wi1[13], a1);
            // layer-2 recurrent part (uses h2 of previous step -- off chain)
            float q0 = bsum2, q1 = 0.f;
#pragma unroll
            for (int m = 0; m < 8; m += 2) {
                q0 = fmaf(hx2[m],     wh2p[m],     q0);
                q1 = fmaf(hx2[m + 1], wh2p[m + 1], q1);
            }
            // layer-1 recurrent butterfly dot
#pragma unroll
            for (int m = 0; m < 8; m += 2) {
                a0 = fmaf(hx1[m],     wh1p[m],     a0);
                a1 = fmaf(hx1[m + 1], wh1p[m + 1], a1);
            }
            float acc = a0 + a1;

            // own-type activation (sigmoid for i,f,o; tanh for g)
            float v0 = fmaf(fast_rcp(1.f + fast_exp2(actScale * acc)), actMul, actAdd);
            // gate exchange: v1=type^1 (DPP), v2=type^2 (swizzle), v3=type^3 (DPP of v2)
            float v2 = swz<0x401F>(v0);        // xor 16 -- the one DS op on the chain
            float v1 = dpp<DPP_XOR8>(v0);      // xor 8
            float v3 = dpp<DPP_XOR8>(v2);      // xor 24
            // P = sigmoid(i)*tanh(g), F = sigmoid(f), O = sigmoid(o)
            float P = b0 ? v1 * v3 : v0 * v2;
            float F = b1 ? (b0 ? v2 : v3) : (b0 ? v0 : v1);
            float O = b1 ? (b0 ? v0 : v1) : (b0 ? v2 : v3);
            c1 = fmaf(F, c1, P);
            float th1 = fmaf(fast_rcp(1.f + fast_exp2(-2.885390082f * c1)), 2.f, -1.f);
            float h1u = O * th1;               // every lane holds h1[own unit]
            butterfly8(h1u, hx1);              // 7 DPP movs (reused next step too)

            // ---- layer 2 ----
            float p0 = q0, p1 = q1;
#pragma unroll
            for (int m = 0; m < 8; m += 2) {
                p0 = fmaf(hx1[m],     wi2p[m],     p0);
                p1 = fmaf(hx1[m + 1], wi2p[m + 1], p1);
            }
            float acc2 = p0 + p1;

            float u0 = fmaf(fast_rcp(1.f + fast_exp2(actScale * acc2)), actMul, actAdd);
            float u2 = swz<0x401F>(u0);
            float u1 = dpp<DPP_XOR8>(u0);
            float u3 = dpp<DPP_XOR8>(u2);
            float P2 = b0 ? u1 * u3 : u0 * u2;
            float F2 = b1 ? (b0 ? u2 : u3) : (b0 ? u0 : u1);
            float O2 = b1 ? (b0 ? u0 : u1) : (b0 ? u2 : u3);
            c2 = fmaf(F2, c2, P2);
            float th2 = fmaf(fast_rcp(1.f + fast_exp2(-2.885390082f * c2)), 2.f, -1.f);
            float h2u = O2 * th2;
            butterfly8(h2u, hx2);
        }
    }

    // ---- BN (eval) + MLP head, one lane per batch element ----
    // At lane g==0 (u==0): hx2[m] = h2[m].
    if (g == 0) {
        float nd[HID];
#pragma unroll
        for (int j = 0; j < HID; ++j) {
            float inv = 1.f / sqrtf(bn_var[j] + BN_EPS);
            nd[j] = bn_gamma[j] * (hx2[j] - bn_mean[j]) * inv + bn_beta[j];
        }
        float acc = b2p[0];
#pragma unroll
        for (int m = 0; m < 4; ++m) {
            float s = b1p[m];
#pragma unroll
            for (int j = 0; j < HID; ++j) s = fmaf(nd[j], w1p[m * HID + j], s);
            s = fmaxf(s, 0.f);
            acc = fmaf(s, w2p[m], acc);
        }
        out[b] = acc;
    }
}

extern "C" void kernel_launch(void* const* d_in, const int* in_sizes, int n_in,
                              void* d_out, int out_size, void* d_ws, size_t ws_size,
                              hipStream_t stream) {
    const float* x        = (const float*)d_in[0];
    const float* Wih1     = (const float*)d_in[1];
    const float* Whh1     = (const float*)d_in[2];
    const float* bih1     = (const float*)d_in[3];
    const float* bhh1     = (const float*)d_in[4];
    const float* Wih2     = (const float*)d_in[5];
    const float* Whh2     = (const float*)d_in[6];
    const float* bih2     = (const float*)d_in[7];
    const float* bhh2     = (const float*)d_in[8];
    const float* bn_gamma = (const float*)d_in[9];
    const float* bn_beta  = (const float*)d_in[10];
    const float* bn_mean  = (const float*)d_in[11];
    const float* bn_var   = (const float*)d_in[12];
    const float* w1p      = (const float*)d_in[13];
    const float* b1p      = (const float*)d_in[14];
    const float* w2p      = (const float*)d_in[15];
    const float* b2p      = (const float*)d_in[16];
    float* out = (float*)d_out;

    const int B = in_sizes[0] / (T_SEQ * INPUT);   // 4096
    dim3 grid(B / 8), block(256);
    hipLaunchKernelGGL(lstm_forex_kernel, grid, block, 0, stream,
                       x, Wih1, Whh1, bih1, bhh1, Wih2, Whh2, bih2, bhh2,
                       bn_gamma, bn_beta, bn_mean, bn_var, w1p, b1p, w2p, b2p, out);
}